// Round 2
// baseline (150.193 us; speedup 1.0000x reference)
//
#include <hip/hip_runtime.h>
#include <hip/hip_bf16.h>
#include <math.h>
#include <stdint.h>

#define SMOOTHING 0.01f

// Combine two online-softmax partials (m1,s1) <- (m1,s1) + (m2,s2)
__device__ __forceinline__ void olsm_combine(float& m, float& s, float mo, float so) {
    float mn = fmaxf(m, mo);
    s = s * __expf(m - mn) + so * __expf(mo - mn);
    m = mn;
}

__device__ __forceinline__ void olsm_push(float& m, float& s, float x) {
    if (x > m) {
        s *= __expf(m - x);
        m = x;
    }
    s += __expf(x - m);
}

__global__ __launch_bounds__(256) void row_loss_kernel(
        const float* __restrict__ y_pred,
        const int*   __restrict__ y_label,
        float*       __restrict__ row_loss,
        int V) {
    const int r   = blockIdx.x;
    const int tid = threadIdx.x;
    const float* __restrict__ row = y_pred + (size_t)r * (size_t)V;

    // 4 independent online-softmax accumulators for ILP
    float m0 = -INFINITY, m1 = -INFINITY, m2 = -INFINITY, m3 = -INFINITY;
    float s0 = 0.f, s1 = 0.f, s2 = 0.f, s3 = 0.f;
    float sx0 = 0.f, sx1 = 0.f, sx2 = 0.f, sx3 = 0.f;

    // Alignment peel: rows are 4B-aligned but not necessarily 16B-aligned
    uintptr_t addr = (uintptr_t)row;
    int head = (int)(((16u - (addr & 15u)) & 15u) >> 2);
    if (head > V) head = V;

    for (int i = tid; i < head; i += 256) {
        float x = row[i];
        sx0 += x;
        olsm_push(m0, s0, x);
    }

    const int nvec = (V - head) >> 2;
    const float4* __restrict__ vrow = (const float4*)(row + head);
    for (int i = tid; i < nvec; i += 256) {
        float4 v = vrow[i];
        sx0 += v.x; olsm_push(m0, s0, v.x);
        sx1 += v.y; olsm_push(m1, s1, v.y);
        sx2 += v.z; olsm_push(m2, s2, v.z);
        sx3 += v.w; olsm_push(m3, s3, v.w);
    }

    const int tail_start = head + (nvec << 2);
    for (int i = tail_start + tid; i < V; i += 256) {
        float x = row[i];
        sx0 += x;
        olsm_push(m0, s0, x);
    }

    // Merge the 4 per-thread accumulators
    olsm_combine(m0, s0, m1, s1);
    olsm_combine(m2, s2, m3, s3);
    olsm_combine(m0, s0, m2, s2);
    float sx = (sx0 + sx1) + (sx2 + sx3);
    float m = m0, s = s0;

    // Wave (64-lane) butterfly reduction
    #pragma unroll
    for (int off = 32; off > 0; off >>= 1) {
        float mo  = __shfl_xor(m, off);
        float so  = __shfl_xor(s, off);
        float sxo = __shfl_xor(sx, off);
        olsm_combine(m, s, mo, so);
        sx += sxo;
    }

    // Cross-wave reduction via LDS (256 threads = 4 waves)
    __shared__ float sm_m[4], sm_s[4], sm_sx[4];
    const int wid  = tid >> 6;
    const int lane = tid & 63;
    if (lane == 0) {
        sm_m[wid] = m; sm_s[wid] = s; sm_sx[wid] = sx;
    }
    __syncthreads();

    if (tid == 0) {
        float M = sm_m[0], S = sm_s[0], SX = sm_sx[0];
        #pragma unroll
        for (int w = 1; w < 4; ++w) {
            olsm_combine(M, S, sm_m[w], sm_s[w]);
            SX += sm_sx[w];
        }
        const float logZ = M + logf(S);
        const int tgt = y_label[r];
        const float tgt_lp = row[tgt] - logZ;
        const float sum_lp = SX - (float)V * logZ;
        const float base  = SMOOTHING / (float)(V - 1);
        const float coeff = 1.0f - SMOOTHING - base;
        row_loss[r] = -(base * sum_lp + coeff * tgt_lp);
    }
}

__global__ __launch_bounds__(1024) void reduce_mean_kernel(
        const float* __restrict__ row_loss,
        float*       __restrict__ out,
        int B) {
    float s = 0.f;
    for (int i = threadIdx.x; i < B; i += 1024) s += row_loss[i];

    #pragma unroll
    for (int off = 32; off > 0; off >>= 1) s += __shfl_xor(s, off);

    __shared__ float sm[16];
    const int wid  = threadIdx.x >> 6;
    const int lane = threadIdx.x & 63;
    if (lane == 0) sm[wid] = s;
    __syncthreads();

    if (threadIdx.x == 0) {
        float t = 0.f;
        #pragma unroll
        for (int w = 0; w < 16; ++w) t += sm[w];
        out[0] = t / (float)B;
    }
}

extern "C" void kernel_launch(void* const* d_in, const int* in_sizes, int n_in,
                              void* d_out, int out_size, void* d_ws, size_t ws_size,
                              hipStream_t stream) {
    const float* y_pred  = (const float*)d_in[0];
    const int*   y_label = (const int*)d_in[1];
    float*       out     = (float*)d_out;
    float*       rl      = (float*)d_ws;

    const int B = in_sizes[1];
    const int V = (int)(in_sizes[0] / (size_t)B);

    row_loss_kernel<<<B, 256, 0, stream>>>(y_pred, y_label, rl, V);
    reduce_mean_kernel<<<1, 1024, 0, stream>>>(rl, out, B);
}